// Round 4
// baseline (177.564 us; speedup 1.0000x reference)
//
#include <hip/hip_runtime.h>
#include <math.h>

// Performer FAVOR+ feature map via bf16 hi/lo split MFMA — LDS-free, barrier-free.
//   out[t][j] = exp2( (x[t].(nrm*proj[j]))*log2e - 0.5*||x[t]||^2*log2e - 4 ) + ratio*eps
// A-fragments loaded straight from global (64B-coalesced, L1-shared across the
// block's 4 waves); hi/lo bf16 conversion in registers; diag via shfl.
// dot = hi*hi + hi*lo + lo*hi (drop lo*lo, rel err ~2^-17; round-2 absmax 3e-8).
//
// Block: 256 thr = 4 waves over 64 tokens x 256 feats; wave w owns feats
// [64w, 64w+64) with B frags (16 x 16B, frag-ordered by prep kernel) in regs.

typedef short bf16x8 __attribute__((ext_vector_type(8)));
typedef float f32x4  __attribute__((ext_vector_type(4)));

__device__ __forceinline__ unsigned short f2bf_rne(float f) {
    unsigned u = __builtin_bit_cast(unsigned, f);
    unsigned r = u + 0x7FFFu + ((u >> 16) & 1u);
    return (unsigned short)(r >> 16);
}

__device__ __forceinline__ void f2bf_hilo(float f, unsigned short& h, unsigned short& l) {
    h = f2bf_rne(f);
    float fh = __builtin_bit_cast(float, (unsigned)h << 16);
    l = f2bf_rne(f - fh);
}

// ---- pre-kernel: proj (256x64 fp32) -> frag-ordered bf16 hi/lo in ws ----
// layout: frag index ((nt*2 + kc)*2 + h), 64 lanes x 8 bf16 each.
__global__ void performer_prep(const float* __restrict__ proj, short* __restrict__ bfrag) {
    int g    = blockIdx.x * 256 + threadIdx.x;   // 0..4095
    int lane = g & 63;
    int h    = (g >> 6) & 1;
    int kc   = (g >> 7) & 1;
    int nt   = g >> 8;                           // 0..15
    int n    = nt * 16 + (lane & 15);
    int kb   = kc * 32 + (lane >> 4) * 8;
    const float nrm = 0.35355339059327373f;      // 64^-0.25
    float4 v0 = *(const float4*)&proj[n * 64 + kb];
    float4 v1 = *(const float4*)&proj[n * 64 + kb + 4];
    float vals[8] = {v0.x, v0.y, v0.z, v0.w, v1.x, v1.y, v1.z, v1.w};
    union { unsigned short us[8]; bf16x8 v; } o;
    #pragma unroll
    for (int j = 0; j < 8; ++j) {
        unsigned short hi, lo;
        f2bf_hilo(vals[j] * nrm, hi, lo);
        o.us[j] = h ? lo : hi;
    }
    *(bf16x8*)&bfrag[g * 8] = o.v;
}

__global__ __launch_bounds__(256, 4)
void performer_fm_kernel(const float* __restrict__ x,
                         const short* __restrict__ bfrag,
                         float* __restrict__ out) {
    const int tid  = threadIdx.x;
    const int wave = tid >> 6;
    const int lane = tid & 63;
    const int q    = lane >> 4;
    const int li   = lane & 15;
    const long t0  = (long)blockIdx.x * 64;

    // ---- B fragments: wave's 4 feature tiles x 2 K-chunks x {hi,lo} ----
    bf16x8 Bh[4][2], Bl[4][2];
    {
        const bf16x8* bw = (const bf16x8*)bfrag;
        #pragma unroll
        for (int nt = 0; nt < 4; ++nt) {
            int ntg = wave * 4 + nt;
            #pragma unroll
            for (int kc = 0; kc < 2; ++kc) {
                Bh[nt][kc] = bw[((ntg * 2 + kc) * 2 + 0) * 64 + lane];
                Bl[nt][kc] = bw[((ntg * 2 + kc) * 2 + 1) * 64 + lane];
            }
        }
    }

    const float LOG2E = 1.4426950408889634f;
    const float NHL2E = -0.7213475204444817f;    // -0.5 * log2(e)
    const float REPS  = 6.25e-6f;                // ratio * eps = 0.0625 * 1e-4

    #pragma unroll
    for (int mt = 0; mt < 4; ++mt) {
        // ---- A fragment straight from global: token t0+mt*16+li, k=q*8..q*8+7 (+32) ----
        const float4* xr = (const float4*)(x + (t0 + mt * 16 + li) * 64);
        float4 a0 = xr[q * 2];
        float4 a1 = xr[q * 2 + 1];
        float4 a2 = xr[8 + q * 2];
        float4 a3 = xr[8 + q * 2 + 1];

        // ---- exact fp32 ||x||^2: 16 local squares, reduce across quad groups ----
        float p = a0.x * a0.x + a0.y * a0.y + a0.z * a0.z + a0.w * a0.w
                + a1.x * a1.x + a1.y * a1.y + a1.z * a1.z + a1.w * a1.w
                + a2.x * a2.x + a2.y * a2.y + a2.z * a2.z + a2.w * a2.w
                + a3.x * a3.x + a3.y * a3.y + a3.z * a3.z + a3.w * a3.w;
        p += __shfl_xor(p, 16);
        p += __shfl_xor(p, 32);                  // lane holds ||x_{t0+mt*16+li}||^2
        float e[4];
        #pragma unroll
        for (int r = 0; r < 4; ++r)              // C row = q*4+r -> need diag of that token
            e[r] = fmaf(NHL2E, __shfl(p, q * 4 + r), -4.0f);

        // ---- register hi/lo bf16 pack ----
        float v0[8] = {a0.x, a0.y, a0.z, a0.w, a1.x, a1.y, a1.z, a1.w};
        float v1[8] = {a2.x, a2.y, a2.z, a2.w, a3.x, a3.y, a3.z, a3.w};
        union { unsigned short us[8]; bf16x8 v; } h0, l0, h1, l1;
        #pragma unroll
        for (int j = 0; j < 8; ++j) {
            f2bf_hilo(v0[j], h0.us[j], l0.us[j]);
            f2bf_hilo(v1[j], h1.us[j], l1.us[j]);
        }

        float* ob = out + (t0 + mt * 16 + q * 4) * 256 + wave * 64 + li;
        #pragma unroll
        for (int nt = 0; nt < 4; ++nt) {
            f32x4 acc = {0.f, 0.f, 0.f, 0.f};
            acc = __builtin_amdgcn_mfma_f32_16x16x32_bf16(l0.v, Bh[nt][0], acc, 0, 0, 0);
            acc = __builtin_amdgcn_mfma_f32_16x16x32_bf16(h0.v, Bl[nt][0], acc, 0, 0, 0);
            acc = __builtin_amdgcn_mfma_f32_16x16x32_bf16(h0.v, Bh[nt][0], acc, 0, 0, 0);
            acc = __builtin_amdgcn_mfma_f32_16x16x32_bf16(l1.v, Bh[nt][1], acc, 0, 0, 0);
            acc = __builtin_amdgcn_mfma_f32_16x16x32_bf16(h1.v, Bl[nt][1], acc, 0, 0, 0);
            acc = __builtin_amdgcn_mfma_f32_16x16x32_bf16(h1.v, Bh[nt][1], acc, 0, 0, 0);
            // C layout: col = li (feat), row = q*4 + r (token-local)
            #pragma unroll
            for (int r = 0; r < 4; ++r)
                ob[r * 256 + nt * 16] =
                    __builtin_amdgcn_exp2f(fmaf(acc[r], LOG2E, e[r])) + REPS;
        }
    }
}

extern "C" void kernel_launch(void* const* d_in, const int* in_sizes, int n_in,
                              void* d_out, int out_size, void* d_ws, size_t ws_size,
                              hipStream_t stream) {
    const float* x    = (const float*)d_in[0];
    const float* proj = (const float*)d_in[1];
    float* out        = (float*)d_out;
    short* bfrag      = (short*)d_ws;            // 64 KB frag-ordered proj
    const int ntok    = in_sizes[0] / 64;        // 131072

    performer_prep<<<16, 256, 0, stream>>>(proj, bfrag);
    performer_fm_kernel<<<ntok / 64, 256, 0, stream>>>(x, bfrag, out);
}

// Round 5
// 170.281 us; speedup vs baseline: 1.0428x; 1.0428x over previous
//
#include <hip/hip_runtime.h>
#include <math.h>

// Performer FAVOR+ feature map — 3-kernel split, bf16 hi/lo MFMA.
//   out[t][j] = exp2( dot*log2e + dlog[t] ) + ratio*eps,
//   dot = x[t].(nrm*proj[j]) via hi*hi + hi*lo + lo*hi (round-2 absmax 3e-8),
//   dlog[t] = -0.5*||x[t]||^2*log2e - 4   (ratio=2^-4 folded into exponent).
//
// prep_b: proj -> frag-ordered bf16 hi/lo (64 KB in ws).
// prep_x: x -> frag-linear bf16 hi/lo (33.5 MB in ws) + dlog (0.5 MB).
// main:   pure streaming: coalesced 16B A/B frag loads, MFMA, exp2, store.
//         512 thr = 8 waves; wave owns 64 tokens x 32 feats; B = 8 frags
//         (32 VGPR); no LDS, no barrier, no cvt -> fits 128-VGPR / 4 w/EU.

typedef short bf16x8 __attribute__((ext_vector_type(8)));
typedef float f32x4  __attribute__((ext_vector_type(4)));

__device__ __forceinline__ unsigned short f2bf_rne(float f) {
    unsigned u = __builtin_bit_cast(unsigned, f);
    unsigned r = u + 0x7FFFu + ((u >> 16) & 1u);
    return (unsigned short)(r >> 16);
}

__device__ __forceinline__ void f2bf_hilo(float f, unsigned short& h, unsigned short& l) {
    h = f2bf_rne(f);
    float fh = __builtin_bit_cast(float, (unsigned)h << 16);
    l = f2bf_rne(f - fh);
}

// ---- prep_b: proj (256x64 fp32) -> frag-ordered bf16 hi/lo ----
// frag index ((ntg*2 + kc)*2 + h), 64 lanes x 8 bf16.
__global__ void performer_prep_b(const float* __restrict__ proj, short* __restrict__ bfrag) {
    int g    = blockIdx.x * 256 + threadIdx.x;   // 0..4095
    int lane = g & 63;
    int h    = (g >> 6) & 1;
    int kc   = (g >> 7) & 1;
    int nt   = g >> 8;                           // 0..15
    int n    = nt * 16 + (lane & 15);
    int kb   = kc * 32 + (lane >> 4) * 8;
    const float nrm = 0.35355339059327373f;      // 64^-0.25
    float4 v0 = *(const float4*)&proj[n * 64 + kb];
    float4 v1 = *(const float4*)&proj[n * 64 + kb + 4];
    float vals[8] = {v0.x, v0.y, v0.z, v0.w, v1.x, v1.y, v1.z, v1.w};
    union { unsigned short us[8]; bf16x8 v; } o;
    #pragma unroll
    for (int j = 0; j < 8; ++j) {
        unsigned short hi, lo;
        f2bf_hilo(vals[j] * nrm, hi, lo);
        o.us[j] = h ? lo : hi;
    }
    *(bf16x8*)&bfrag[g * 8] = o.v;
}

// ---- prep_x: x -> frag-linear bf16 hi/lo + dlog ----
// Tile = 16 tokens. frag f: 0=hi(k kc0) 1=lo(kc0) 2=hi(kc1) 3=lo(kc1);
// addr = ((tile*4 + f)*64 + lane)*8 shorts. One wave per tile.
__global__ __launch_bounds__(256, 4)
void performer_prep_x(const float* __restrict__ x, short* __restrict__ xfrag,
                      float* __restrict__ dlog) {
    const int wave = threadIdx.x >> 6;
    const int lane = threadIdx.x & 63;
    const int q    = lane >> 4;
    const int li   = lane & 15;
    const long m   = (long)blockIdx.x * 4 + wave;   // tile index
    const long tok = m * 16 + li;

    const float4* xr = (const float4*)(x + tok * 64);
    float4 a0 = xr[q * 2];          // k = q*8 .. q*8+3
    float4 a1 = xr[q * 2 + 1];      // k = q*8+4 .. q*8+7
    float4 a2 = xr[8 + q * 2];      // k = 32+q*8 ..
    float4 a3 = xr[8 + q * 2 + 1];

    float p = a0.x * a0.x + a0.y * a0.y + a0.z * a0.z + a0.w * a0.w
            + a1.x * a1.x + a1.y * a1.y + a1.z * a1.z + a1.w * a1.w
            + a2.x * a2.x + a2.y * a2.y + a2.z * a2.z + a2.w * a2.w
            + a3.x * a3.x + a3.y * a3.y + a3.z * a3.z + a3.w * a3.w;
    p += __shfl_xor(p, 16);
    p += __shfl_xor(p, 32);         // full ||x_tok||^2
    const float NHL2E = -0.7213475204444817f;    // -0.5*log2(e)
    if (q == 0) dlog[tok] = fmaf(NHL2E, p, -4.0f);

    float v0[8] = {a0.x, a0.y, a0.z, a0.w, a1.x, a1.y, a1.z, a1.w};
    float v1[8] = {a2.x, a2.y, a2.z, a2.w, a3.x, a3.y, a3.z, a3.w};
    union { unsigned short us[8]; bf16x8 v; } h0, l0, h1, l1;
    #pragma unroll
    for (int j = 0; j < 8; ++j) {
        f2bf_hilo(v0[j], h0.us[j], l0.us[j]);
        f2bf_hilo(v1[j], h1.us[j], l1.us[j]);
    }
    bf16x8* xf = (bf16x8*)xfrag;
    const long base = m * 4 * 64 + lane;
    xf[base]           = h0.v;
    xf[base + 64]      = l0.v;
    xf[base + 2 * 64]  = h1.v;
    xf[base + 3 * 64]  = l1.v;
}

// ---- main: 8 waves, wave owns 64 tokens x 32 feats ----
__global__ __launch_bounds__(512, 4)
void performer_fm_kernel(const short* __restrict__ xfrag,
                         const short* __restrict__ bfrag,
                         const float* __restrict__ dlog,
                         float* __restrict__ out) {
    const int wave = threadIdx.x >> 6;
    const int lane = threadIdx.x & 63;
    const int q    = lane >> 4;
    const int li   = lane & 15;
    const long t0  = (long)blockIdx.x * 64;

    // B fragments: 2 feat tiles x 2 K-chunks x {hi,lo} = 8 frags (32 VGPR)
    bf16x8 Bh[2][2], Bl[2][2];
    {
        const bf16x8* bw = (const bf16x8*)bfrag;
        #pragma unroll
        for (int nt = 0; nt < 2; ++nt) {
            int ntg = wave * 2 + nt;
            #pragma unroll
            for (int kc = 0; kc < 2; ++kc) {
                Bh[nt][kc] = bw[((ntg * 2 + kc) * 2 + 0) * 64 + lane];
                Bl[nt][kc] = bw[((ntg * 2 + kc) * 2 + 1) * 64 + lane];
            }
        }
    }

    const bf16x8* xf = (const bf16x8*)xfrag;
    const float LOG2E = 1.4426950408889634f;
    const float REPS  = 6.25e-6f;                // ratio*eps

    #pragma unroll
    for (int mt = 0; mt < 4; ++mt) {
        const long tile = (long)blockIdx.x * 4 + mt;
        const long ab   = tile * 4 * 64 + lane;
        bf16x8 ah0 = xf[ab];
        bf16x8 al0 = xf[ab + 64];
        bf16x8 ah1 = xf[ab + 2 * 64];
        bf16x8 al1 = xf[ab + 3 * 64];
        float4 dl  = *(const float4*)&dlog[t0 + mt * 16 + q * 4];

        float* ob = out + (t0 + mt * 16 + q * 4) * 256 + wave * 32 + li;
        #pragma unroll
        for (int nt = 0; nt < 2; ++nt) {
            f32x4 acc = {0.f, 0.f, 0.f, 0.f};
            acc = __builtin_amdgcn_mfma_f32_16x16x32_bf16(al0, Bh[nt][0], acc, 0, 0, 0);
            acc = __builtin_amdgcn_mfma_f32_16x16x32_bf16(ah0, Bl[nt][0], acc, 0, 0, 0);
            acc = __builtin_amdgcn_mfma_f32_16x16x32_bf16(ah0, Bh[nt][0], acc, 0, 0, 0);
            acc = __builtin_amdgcn_mfma_f32_16x16x32_bf16(al1, Bh[nt][1], acc, 0, 0, 0);
            acc = __builtin_amdgcn_mfma_f32_16x16x32_bf16(ah1, Bl[nt][1], acc, 0, 0, 0);
            acc = __builtin_amdgcn_mfma_f32_16x16x32_bf16(ah1, Bh[nt][1], acc, 0, 0, 0);
            // C layout: col = li (feat), row = q*4 + r (token-local)
            const float e0 = dl.x, e1 = dl.y, e2 = dl.z, e3 = dl.w;
            ob[0 * 256 + nt * 16] = __builtin_amdgcn_exp2f(fmaf(acc[0], LOG2E, e0)) + REPS;
            ob[1 * 256 + nt * 16] = __builtin_amdgcn_exp2f(fmaf(acc[1], LOG2E, e1)) + REPS;
            ob[2 * 256 + nt * 16] = __builtin_amdgcn_exp2f(fmaf(acc[2], LOG2E, e2)) + REPS;
            ob[3 * 256 + nt * 16] = __builtin_amdgcn_exp2f(fmaf(acc[3], LOG2E, e3)) + REPS;
        }
    }
}

extern "C" void kernel_launch(void* const* d_in, const int* in_sizes, int n_in,
                              void* d_out, int out_size, void* d_ws, size_t ws_size,
                              hipStream_t stream) {
    const float* x    = (const float*)d_in[0];
    const float* proj = (const float*)d_in[1];
    float* out        = (float*)d_out;
    const int ntok    = in_sizes[0] / 64;        // 131072

    char* ws    = (char*)d_ws;
    short* bfrag = (short*)ws;                          // 64 KB
    short* xfrag = (short*)(ws + 65536);                // 33.55 MB
    float* dlog  = (float*)(ws + 65536 + (size_t)ntok * 64 * 2 * 2);  // 0.5 MB

    performer_prep_b<<<16, 256, 0, stream>>>(proj, bfrag);
    performer_prep_x<<<ntok / 64, 256, 0, stream>>>(x, xfrag, dlog);
    performer_fm_kernel<<<ntok / 64, 512, 0, stream>>>(xfrag, bfrag, dlog, out);
}

// Round 6
// 161.492 us; speedup vs baseline: 1.0995x; 1.0544x over previous
//
#include <hip/hip_runtime.h>
#include <math.h>

// Performer FAVOR+ feature map — fused single main kernel + tiny B-prep.
//   out[t][j] = exp2( dot*log2e + dlog[t] ) + ratio*eps
//   dot = x[t].(nrm*proj[j]) via bf16 hi/lo 3-term MFMA (absmax 3e-8, verified)
//   dlog[t] = -0.5*||x[t]||^2*log2e - 4   (ratio=2^-4 folded into exponent)
//
// Main: 512 thr = 8 waves, tile 128 tokens x 256 feats.
//   Stage: wave w converts its 16 tokens -> hi/lo bf16 frags in LDS (32 KB),
//          conflict-free ds_write_b128 at base+lane*16; dlog via 2 shfl.
//   One barrier. Compute: wave w = feats [32w,32w+32): 8 B-frags in regs
//   (32 VGPR, slim), 8 mt x { 4 ds_read_b128 + 2 nt x (6 MFMA + exp2 + st) }.

typedef short bf16x8 __attribute__((ext_vector_type(8)));
typedef float f32x4  __attribute__((ext_vector_type(4)));

__device__ __forceinline__ unsigned short f2bf_rne(float f) {
    unsigned u = __builtin_bit_cast(unsigned, f);
    unsigned r = u + 0x7FFFu + ((u >> 16) & 1u);
    return (unsigned short)(r >> 16);
}

__device__ __forceinline__ void f2bf_hilo(float f, unsigned short& h, unsigned short& l) {
    h = f2bf_rne(f);
    float fh = __builtin_bit_cast(float, (unsigned)h << 16);
    l = f2bf_rne(f - fh);
}

// ---- prep_b: proj (256x64 fp32) -> frag-ordered bf16 hi/lo (64 KB) ----
// frag index ((ntg*2 + kc)*2 + h), 64 lanes x 8 bf16.
__global__ void performer_prep_b(const float* __restrict__ proj, short* __restrict__ bfrag) {
    int g    = blockIdx.x * 256 + threadIdx.x;   // 0..4095
    int lane = g & 63;
    int h    = (g >> 6) & 1;
    int kc   = (g >> 7) & 1;
    int nt   = g >> 8;                           // 0..15
    int n    = nt * 16 + (lane & 15);
    int kb   = kc * 32 + (lane >> 4) * 8;
    const float nrm = 0.35355339059327373f;      // 64^-0.25
    float4 v0 = *(const float4*)&proj[n * 64 + kb];
    float4 v1 = *(const float4*)&proj[n * 64 + kb + 4];
    float vals[8] = {v0.x, v0.y, v0.z, v0.w, v1.x, v1.y, v1.z, v1.w};
    union { unsigned short us[8]; bf16x8 v; } o;
    #pragma unroll
    for (int j = 0; j < 8; ++j) {
        unsigned short hi, lo;
        f2bf_hilo(vals[j] * nrm, hi, lo);
        o.us[j] = h ? lo : hi;
    }
    *(bf16x8*)&bfrag[g * 8] = o.v;
}

// ---- fused main ----
__global__ __launch_bounds__(512, 4)
void performer_fm_kernel(const float* __restrict__ x,
                         const short* __restrict__ bfrag,
                         float* __restrict__ out) {
    // A frags: 8 mt x 4 frags(h0,l0,h1,l1) x 64 lanes x 16 B = 32 KB
    __shared__ __align__(16) short Af[8 * 4 * 64 * 8];
    __shared__ float dlg[128];

    const int wave = threadIdx.x >> 6;
    const int lane = threadIdx.x & 63;
    const int q    = lane >> 4;
    const int li   = lane & 15;
    const long t0  = (long)blockIdx.x * 128;

    // ---- staging: wave w -> tokens [t0+16w, t0+16w+16) ----
    const float4* xr = (const float4*)(x + (t0 + wave * 16 + li) * 64);
    float4 a0 = xr[q * 2];          // k = q*8 .. q*8+3
    float4 a1 = xr[q * 2 + 1];      // k = q*8+4 .. q*8+7
    float4 a2 = xr[8 + q * 2];      // k = 32+q*8 ..
    float4 a3 = xr[8 + q * 2 + 1];

    // ---- B fragments (L2-hot, independent of staging) ----
    bf16x8 Bh[2][2], Bl[2][2];
    {
        const bf16x8* bw = (const bf16x8*)bfrag;
        #pragma unroll
        for (int nt = 0; nt < 2; ++nt) {
            int ntg = wave * 2 + nt;
            #pragma unroll
            for (int kc = 0; kc < 2; ++kc) {
                Bh[nt][kc] = bw[((ntg * 2 + kc) * 2 + 0) * 64 + lane];
                Bl[nt][kc] = bw[((ntg * 2 + kc) * 2 + 1) * 64 + lane];
            }
        }
    }

    // exact fp32 ||x||^2 for token (16w+li): reduce across q groups
    float p = a0.x * a0.x + a0.y * a0.y + a0.z * a0.z + a0.w * a0.w
            + a1.x * a1.x + a1.y * a1.y + a1.z * a1.z + a1.w * a1.w
            + a2.x * a2.x + a2.y * a2.y + a2.z * a2.z + a2.w * a2.w
            + a3.x * a3.x + a3.y * a3.y + a3.z * a3.z + a3.w * a3.w;
    p += __shfl_xor(p, 16);
    p += __shfl_xor(p, 32);
    const float NHL2E = -0.7213475204444817f;    // -0.5*log2(e)
    if (q == 0) dlg[wave * 16 + li] = fmaf(NHL2E, p, -4.0f);

    // register hi/lo pack -> LDS frags (conflict-free b128 at base+lane*16)
    {
        float v0[8] = {a0.x, a0.y, a0.z, a0.w, a1.x, a1.y, a1.z, a1.w};
        float v1[8] = {a2.x, a2.y, a2.z, a2.w, a3.x, a3.y, a3.z, a3.w};
        union { unsigned short us[8]; bf16x8 v; } h0, l0, h1, l1;
        #pragma unroll
        for (int j = 0; j < 8; ++j) {
            f2bf_hilo(v0[j], h0.us[j], l0.us[j]);
            f2bf_hilo(v1[j], h1.us[j], l1.us[j]);
        }
        bf16x8* As = (bf16x8*)Af;
        const int base = wave * 4 * 64 + lane;   // mt = wave
        As[base]       = h0.v;
        As[base + 64]  = l0.v;
        As[base + 128] = h1.v;
        As[base + 192] = l1.v;
    }
    __syncthreads();

    const bf16x8* As = (const bf16x8*)Af;
    const float LOG2E = 1.4426950408889634f;
    const float REPS  = 6.25e-6f;                // ratio*eps

    #pragma unroll 2
    for (int mt = 0; mt < 8; ++mt) {
        const int ab = mt * 256 + lane;
        bf16x8 ah0 = As[ab];
        bf16x8 al0 = As[ab + 64];
        bf16x8 ah1 = As[ab + 128];
        bf16x8 al1 = As[ab + 192];
        float4 dl  = *(const float4*)&dlg[mt * 16 + q * 4];

        float* ob = out + (t0 + mt * 16 + q * 4) * 256 + wave * 32 + li;
        #pragma unroll
        for (int nt = 0; nt < 2; ++nt) {
            f32x4 acc = {0.f, 0.f, 0.f, 0.f};
            acc = __builtin_amdgcn_mfma_f32_16x16x32_bf16(al0, Bh[nt][0], acc, 0, 0, 0);
            acc = __builtin_amdgcn_mfma_f32_16x16x32_bf16(ah0, Bl[nt][0], acc, 0, 0, 0);
            acc = __builtin_amdgcn_mfma_f32_16x16x32_bf16(ah0, Bh[nt][0], acc, 0, 0, 0);
            acc = __builtin_amdgcn_mfma_f32_16x16x32_bf16(al1, Bh[nt][1], acc, 0, 0, 0);
            acc = __builtin_amdgcn_mfma_f32_16x16x32_bf16(ah1, Bl[nt][1], acc, 0, 0, 0);
            acc = __builtin_amdgcn_mfma_f32_16x16x32_bf16(ah1, Bh[nt][1], acc, 0, 0, 0);
            // C layout: col = li (feat), row = q*4 + r (token-local)
            ob[0 * 256 + nt * 16] = __builtin_amdgcn_exp2f(fmaf(acc[0], LOG2E, dl.x)) + REPS;
            ob[1 * 256 + nt * 16] = __builtin_amdgcn_exp2f(fmaf(acc[1], LOG2E, dl.y)) + REPS;
            ob[2 * 256 + nt * 16] = __builtin_amdgcn_exp2f(fmaf(acc[2], LOG2E, dl.z)) + REPS;
            ob[3 * 256 + nt * 16] = __builtin_amdgcn_exp2f(fmaf(acc[3], LOG2E, dl.w)) + REPS;
        }
    }
}

extern "C" void kernel_launch(void* const* d_in, const int* in_sizes, int n_in,
                              void* d_out, int out_size, void* d_ws, size_t ws_size,
                              hipStream_t stream) {
    const float* x    = (const float*)d_in[0];
    const float* proj = (const float*)d_in[1];
    float* out        = (float*)d_out;
    short* bfrag      = (short*)d_ws;            // 64 KB frag-ordered proj
    const int ntok    = in_sizes[0] / 64;        // 131072

    performer_prep_b<<<16, 256, 0, stream>>>(proj, bfrag);
    performer_fm_kernel<<<ntok / 128, 512, 0, stream>>>(x, bfrag, out);
}